// Round 9
// baseline (149.724 us; speedup 1.0000x reference)
//
#include <hip/hip_runtime.h>

#define NITER 3
#define LAMBDA 0.01f
#define EPS 1e-9f
#define LOG2PI 1.8378770664093453f

#define DIN 12
#define CIN 8
#define NI 216      // 27 * 8 input capsule-taps
#define NO 16       // output capsules
#define PPAD 20     // sPT row stride (floats)
#define RSTR 220    // sRaT row stride: 880B rows, 16B-aligned, +8p bank shift for softmax reads

// 1024 threads = 16 o x 64 j (wave w <-> o=w). Thread (o,j) owns taps i = j+64k
// (k=0..3, padded to 256). Votes vo[4][16] = 64 VGPR -> whole kernel fits in
// ~120 arch VGPRs at 4 waves/EU (no AGPR shuffling, 2x occupancy vs R8).
__global__ __launch_bounds__(1024) __attribute__((amdgpu_waves_per_eu(4, 4)))
void caps_em_kernel(const float* __restrict__ pose,
                    const float* __restrict__ act,
                    const float* __restrict__ W,
                    const float* __restrict__ beta_v,
                    const float* __restrict__ beta_a,
                    float* __restrict__ out)
{
    // sPT[i][c*4+k] = P[i][k*4+c]  (pose columns contiguous; prologue-only use)
    __shared__ __align__(16) float sPT[NI][PPAD];
    __shared__ __align__(16) float sRaT[NO][RSTR];   // Ra transposed [o][i]
    __shared__ float sAct[NI];
    __shared__ __align__(16) float sPoseM[NO][16];   // row-major [o][r*4+c]
    __shared__ __align__(16) float sIvM[NO][16];
    __shared__ float sCo[NO];

    const int t = threadIdx.x;
    const int b = blockIdx.x;            // 0..999 -> (od,oh,ow)
    const int od = b / 100;
    const int rem = b - od * 100;
    const int oh = rem / 10;
    const int ow = rem - oh * 10;

    const int o = t >> 6;                // output capsule == wave id
    const int j = t & 63;                // i-lane 0..63

    // ---------- W loads issued first (latency hides under LDS staging) ----------
    const float4* W4 = (const float4*)W;        // idx = (i*16 + o)*4 + r
    float4 w[4][4];
#pragma unroll
    for (int k = 0; k < 4; ++k) {
        const int iw = min(j + 64 * k, NI - 1);   // clamp pad taps (ra=0 kills them)
        const float4* Wp = W4 + (iw * 16 + o) * 4;
        w[k][0] = Wp[0];
        w[k][1] = Wp[1];
        w[k][2] = Wp[2];
        w[k][3] = Wp[3];
    }

    // ---------- stage P (transposed) + act ----------
    if (t < NI * 4) {
        int i = t >> 2, q = t & 3;       // q = source row of the 4x4
        int ci = i & 7, n = i >> 3;
        int kw = n % 3, n2 = n / 3;
        int kh = n2 % 3, kd = n2 / 3;
        const float4 v = *(const float4*)&pose[((((od + kd) * DIN + (oh + kh)) * DIN + (ow + kw)) * CIN + ci) * 16 + q * 4];
        sPT[i][0 + q]  = v.x;
        sPT[i][4 + q]  = v.y;
        sPT[i][8 + q]  = v.z;
        sPT[i][12 + q] = v.w;
    }
    if (t < NI) {
        int i = t;
        int ci = i & 7, n = i >> 3;
        int kw = n % 3, n2 = n / 3;
        int kh = n2 % 3, kd = n2 / 3;
        sAct[i] = act[(((od + kd) * DIN + (oh + kh)) * DIN + (ow + kw)) * CIN + ci] + EPS;
    }
    const float bv_o = beta_v[o];
    const float ba_o = beta_a[o];
    __syncthreads();

    // ---------- compute votes ONCE into registers: vo[k][rr*4+cc] ----------
    float vo[4][16];
#pragma unroll
    for (int k = 0; k < 4; ++k) {
        const int ip = min(j + 64 * k, NI - 1);
#pragma unroll
        for (int cc = 0; cc < 4; ++cc) {
            const float4 pt = *(const float4*)&sPT[ip][cc * 4];   // P[0..3][cc]
#pragma unroll
            for (int rr = 0; rr < 4; ++rr) {
                float v = w[k][rr].x * pt.x;
                v = fmaf(w[k][rr].y, pt.y, v);
                v = fmaf(w[k][rr].z, pt.z, v);
                v = fmaf(w[k][rr].w, pt.w, v);
                vo[k][rr * 4 + cc] = v;
            }
        }
    }

    const int b5 = (j >> 5) & 1, b4 = (j >> 4) & 1, b3 = (j >> 3) & 1, b2 = (j >> 2) & 1;
    const bool lastPartial = (j >= 24);  // k=3 tap i=192+j valid only for j<24

    for (int it = 0; it < NITER; ++it) {
        // ---------- m-step: moments from stored votes ----------
        float m1[16], m2[16];
#pragma unroll
        for (int q = 0; q < 16; ++q) { m1[q] = 0.f; m2[q] = 0.f; }
        float rs = 0.f;
#pragma unroll
        for (int k = 0; k < 4; ++k) {
            const int ip = min(j + 64 * k, NI - 1);
            float ra = (it == 0) ? sAct[ip] * 0.0625f : sRaT[o][ip];
            if (k == 3 && lastPartial) ra = 0.f;   // pad taps contribute nothing
            rs += ra;
#pragma unroll
            for (int q = 0; q < 16; ++q) {
                const float v  = vo[k][q];
                const float rv = ra * v;
                m1[q] += rv;
                m2[q] = fmaf(rv, v, m2[q]);
            }
        }

        // ---------- register-halving shuffle tree over the 64 j-lanes ----------
        // 4 halvings (xor 32/16/8/4) -> lane holds element e = j>>2 (partial over
        // its lane class); 2 dup-adds (xor 2/1) complete the sum (4-fold dup).
#pragma unroll
        for (int q = 0; q < 8; ++q) {
            float s1 = b5 ? m1[q] : m1[q + 8];
            float s2 = b5 ? m2[q] : m2[q + 8];
            m1[q] = (b5 ? m1[q + 8] : m1[q]) + __shfl_xor(s1, 32);
            m2[q] = (b5 ? m2[q + 8] : m2[q]) + __shfl_xor(s2, 32);
        }
#pragma unroll
        for (int q = 0; q < 4; ++q) {
            float s1 = b4 ? m1[q] : m1[q + 4];
            float s2 = b4 ? m2[q] : m2[q + 4];
            m1[q] = (b4 ? m1[q + 4] : m1[q]) + __shfl_xor(s1, 16);
            m2[q] = (b4 ? m2[q + 4] : m2[q]) + __shfl_xor(s2, 16);
        }
#pragma unroll
        for (int q = 0; q < 2; ++q) {
            float s1 = b3 ? m1[q] : m1[q + 2];
            float s2 = b3 ? m2[q] : m2[q + 2];
            m1[q] = (b3 ? m1[q + 2] : m1[q]) + __shfl_xor(s1, 8);
            m2[q] = (b3 ? m2[q + 2] : m2[q]) + __shfl_xor(s2, 8);
        }
        {
            float s1 = b2 ? m1[0] : m1[1];
            float s2 = b2 ? m2[0] : m2[1];
            m1[0] = (b2 ? m1[1] : m1[0]) + __shfl_xor(s1, 4);
            m2[0] = (b2 ? m2[1] : m2[0]) + __shfl_xor(s2, 4);
        }
        m1[0] += __shfl_xor(m1[0], 2);
        m2[0] += __shfl_xor(m2[0], 2);
        m1[0] += __shfl_xor(m1[0], 1);
        m2[0] += __shfl_xor(m2[0], 1);
        rs += __shfl_xor(rs, 32);
        rs += __shfl_xor(rs, 16);
        rs += __shfl_xor(rs, 8);
        rs += __shfl_xor(rs, 4);
        rs += __shfl_xor(rs, 2);
        rs += __shfl_xor(rs, 1);
        const int e = j >> 2;            // this lane's pose element (row-major)

        const float inv_rs = 1.0f / rs;
        const float pe = m1[0] * inv_rs;
        const float ve = fmaxf(m2[0] * inv_rs - pe * pe, 0.0f) + EPS;
        const float lv = __logf(ve);

        // SL = sum log_var over 16 elements (each e lives on 4 lanes -> x0.25)
        float SL = lv;
        SL += __shfl_xor(SL, 1);
        SL += __shfl_xor(SL, 2);
        SL += __shfl_xor(SL, 4);
        SL += __shfl_xor(SL, 8);
        SL += __shfl_xor(SL, 16);
        SL += __shfl_xor(SL, 32);
        SL *= 0.25f;

        const float cost  = rs * (16.0f * bv_o + 0.5f * SL);
        const float logit = LAMBDA * (ba_o - cost);

        if (it == NITER - 1) {
            if ((j & 3) == 0) out[(b * NO + o) * 16 + e] = pe;
            if (j == 0) out[256000 + b * NO + o] = 1.0f / (1.0f + __expf(-logit));
            return;
        }

        const float log_a = (logit >= 0.0f) ? -log1pf(__expf(-logit))
                                            : logit - log1pf(__expf(logit));
        if ((j & 3) == 0) {
            sPoseM[o][e] = pe;
            sIvM[o][e]   = 1.0f / ve;
        }
        if (j == 0) sCo[o] = log_a - 0.5f * SL - 8.0f * LOG2PI;
        __syncthreads();   // B2: pose/iv/Co ready

        // ---------- e-step: q-form from stored votes (pv/iv broadcast reads) ----------
        {
            float pv[16], iv16[16];
            *(float4*)&pv[0]    = *(const float4*)&sPoseM[o][0];
            *(float4*)&pv[4]    = *(const float4*)&sPoseM[o][4];
            *(float4*)&pv[8]    = *(const float4*)&sPoseM[o][8];
            *(float4*)&pv[12]   = *(const float4*)&sPoseM[o][12];
            *(float4*)&iv16[0]  = *(const float4*)&sIvM[o][0];
            *(float4*)&iv16[4]  = *(const float4*)&sIvM[o][4];
            *(float4*)&iv16[8]  = *(const float4*)&sIvM[o][8];
            *(float4*)&iv16[12] = *(const float4*)&sIvM[o][12];
            const float Co = sCo[o];
#pragma unroll
            for (int k = 0; k < 4; ++k) {
                const int i = j + 64 * k;
                float q = 0.f;
#pragma unroll
                for (int qq = 0; qq < 16; ++qq) {
                    const float d = vo[k][qq] - pv[qq];
                    q = fmaf(d * d, iv16[qq], q);
                }
                if (!(k == 3 && lastPartial)) {
                    sRaT[o][i] = Co - 0.5f * q;   // pre-normalization logit
                }
            }
        }
        __syncthreads();   // B3: logits ready

        // ---------- R update: softmax over o, times act (4 threads per i) ----------
        if (t < NI * 4) {
            const int i = t >> 2, p = t & 3;     // lanes 4i..4i+3 share i
            float l[4];
            float mx = -1e30f;
#pragma unroll
            for (int q = 0; q < 4; ++q) { l[q] = sRaT[p * 4 + q][i]; mx = fmaxf(mx, l[q]); }
            mx = fmaxf(mx, __shfl_xor(mx, 1));
            mx = fmaxf(mx, __shfl_xor(mx, 2));
            float s = 0.f;
#pragma unroll
            for (int q = 0; q < 4; ++q) { l[q] = __expf(l[q] - mx); s += l[q]; }
            s += __shfl_xor(s, 1);
            s += __shfl_xor(s, 2);
            const float sc = sAct[i] / s;
#pragma unroll
            for (int q = 0; q < 4; ++q) sRaT[p * 4 + q][i] = sc * l[q];
        }
        __syncthreads();   // B4: Ra ready
    }
}

extern "C" void kernel_launch(void* const* d_in, const int* in_sizes, int n_in,
                              void* d_out, int out_size, void* d_ws, size_t ws_size,
                              hipStream_t stream) {
    const float* pose = (const float*)d_in[0];
    const float* actv = (const float*)d_in[1];
    const float* W    = (const float*)d_in[2];
    const float* bv   = (const float*)d_in[3];
    const float* ba   = (const float*)d_in[4];
    float* out = (float*)d_out;
    caps_em_kernel<<<dim3(1000), dim3(1024), 0, stream>>>(pose, actv, W, bv, ba, out);
}

// Round 10
// 138.301 us; speedup vs baseline: 1.0826x; 1.0826x over previous
//
#include <hip/hip_runtime.h>
#include <hip/hip_fp16.h>

#define NITER 3
#define LAMBDA 0.01f
#define EPS 1e-9f
#define LOG2PI 1.8378770664093453f

#define DIN 12
#define CIN 8
#define NI 216      // 27 * 8 input capsule-taps
#define NO 16       // output capsules
#define PPAD 20     // sPT row stride (floats)
#define RSTR 216    // sRaT row stride (floats)

// 512 threads = 16 o x 32 j. Thread (o,j) owns taps i = j+32k (k=0..6, padded to 224).
// Iteration-invariant votes stored as PACKED FP16 pairs (vop[7][8] = 56 VGPR vs 112
// for fp32): loop-peak demand ~105 regs fits the RA's natural 128-reg target for
// 512-thr blocks (R4/R5 evidence) -> no AGPR moves, no scratch, 2 blocks/CU.
__global__ __launch_bounds__(512)
void caps_em_kernel(const float* __restrict__ pose,
                    const float* __restrict__ act,
                    const float* __restrict__ W,
                    const float* __restrict__ beta_v,
                    const float* __restrict__ beta_a,
                    float* __restrict__ out)
{
    // sPT[i][c*4+k] = P[i][k*4+c]  (pose columns contiguous; prologue-only use)
    __shared__ __align__(16) float sPT[NI][PPAD];
    __shared__ __align__(16) float sRaT[NO][RSTR];   // Ra transposed [o][i]
    __shared__ float sAct[NI];
    __shared__ __align__(16) float sPoseM[NO][16];   // row-major [o][r*4+c]
    __shared__ __align__(16) float sIvM[NO][16];
    __shared__ float sCo[NO];

    const int t = threadIdx.x;
    const int b = blockIdx.x;            // 0..999 -> (od,oh,ow)
    const int od = b / 100;
    const int rem = b - od * 100;
    const int oh = rem / 10;
    const int ow = rem - oh * 10;

    const int o = t >> 5;                // output capsule 0..15
    const int j = t & 31;                // i-lane 0..31

    // ---------- W loads issued first (latency hides under LDS staging) ----------
    const float4* W4 = (const float4*)W;        // idx = (i*16 + o)*4 + r
    float4 w[7][4];
#pragma unroll
    for (int k = 0; k < 7; ++k) {
        const int iw = min(j + 32 * k, NI - 1);   // clamp pad taps (ra=0 kills them)
        const float4* Wp = W4 + (iw * 16 + o) * 4;
        w[k][0] = Wp[0];
        w[k][1] = Wp[1];
        w[k][2] = Wp[2];
        w[k][3] = Wp[3];
    }

    // ---------- stage P (transposed) + act ----------
    for (int u = t; u < NI * 4; u += 512) {
        int i = u >> 2, q = u & 3;       // q = source row of the 4x4
        int ci = i & 7, n = i >> 3;
        int kw = n % 3, n2 = n / 3;
        int kh = n2 % 3, kd = n2 / 3;
        const float4 v = *(const float4*)&pose[((((od + kd) * DIN + (oh + kh)) * DIN + (ow + kw)) * CIN + ci) * 16 + q * 4];
        sPT[i][0 + q]  = v.x;
        sPT[i][4 + q]  = v.y;
        sPT[i][8 + q]  = v.z;
        sPT[i][12 + q] = v.w;
    }
    if (t < NI) {
        int i = t;
        int ci = i & 7, n = i >> 3;
        int kw = n % 3, n2 = n / 3;
        int kh = n2 % 3, kd = n2 / 3;
        sAct[i] = act[(((od + kd) * DIN + (oh + kh)) * DIN + (ow + kw)) * CIN + ci] + EPS;
    }
    const float bv_o = beta_v[o];
    const float ba_o = beta_a[o];
    __syncthreads();

    // ---------- compute votes ONCE; pack fp16 pairs: vop[k][p] = (e=2p, e=2p+1) ----------
    __half2 vop[7][8];
#pragma unroll
    for (int k = 0; k < 7; ++k) {
        const int ip = min(j + 32 * k, NI - 1);
        float v16[16];
#pragma unroll
        for (int cc = 0; cc < 4; ++cc) {
            const float4 pt = *(const float4*)&sPT[ip][cc * 4];   // P[0..3][cc]
#pragma unroll
            for (int rr = 0; rr < 4; ++rr) {
                float v = w[k][rr].x * pt.x;
                v = fmaf(w[k][rr].y, pt.y, v);
                v = fmaf(w[k][rr].z, pt.z, v);
                v = fmaf(w[k][rr].w, pt.w, v);
                v16[rr * 4 + cc] = v;
            }
        }
#pragma unroll
        for (int p = 0; p < 8; ++p) {
            vop[k][p] = __floats2half2_rn(v16[2 * p], v16[2 * p + 1]);
        }
    }

    const int b4 = (j >> 4) & 1, b3 = (j >> 3) & 1, b2 = (j >> 2) & 1, b1 = (j >> 1) & 1;
    const bool lastPartial = (j >= 24);  // k=6 tap i=192+j valid only for j<24

    for (int it = 0; it < NITER; ++it) {
        // ---------- m-step: moments from stored (fp16) votes ----------
        float m1[16], m2[16];
#pragma unroll
        for (int q = 0; q < 16; ++q) { m1[q] = 0.f; m2[q] = 0.f; }
        float rs = 0.f;
#pragma unroll
        for (int k = 0; k < 7; ++k) {
            const int ip = min(j + 32 * k, NI - 1);
            float ra = (it == 0) ? sAct[ip] * 0.0625f : sRaT[o][ip];
            if (k == 6 && lastPartial) ra = 0.f;   // pad taps contribute nothing
            rs += ra;
#pragma unroll
            for (int p = 0; p < 8; ++p) {
                const float2 f = __half22float2(vop[k][p]);
                const float rv0 = ra * f.x;
                const float rv1 = ra * f.y;
                m1[2 * p]     += rv0;
                m1[2 * p + 1] += rv1;
                m2[2 * p]     = fmaf(rv0, f.x, m2[2 * p]);
                m2[2 * p + 1] = fmaf(rv1, f.y, m2[2 * p + 1]);
            }
        }

        // ---------- register-halving shuffle tree over the 32 j-lanes ----------
        // After 4 halvings + final xor1, lane holds element e = j>>1 (dup over bit0).
#pragma unroll
        for (int q = 0; q < 8; ++q) {
            float s1 = b4 ? m1[q] : m1[q + 8];
            float s2 = b4 ? m2[q] : m2[q + 8];
            m1[q] = (b4 ? m1[q + 8] : m1[q]) + __shfl_xor(s1, 16);
            m2[q] = (b4 ? m2[q + 8] : m2[q]) + __shfl_xor(s2, 16);
        }
#pragma unroll
        for (int q = 0; q < 4; ++q) {
            float s1 = b3 ? m1[q] : m1[q + 4];
            float s2 = b3 ? m2[q] : m2[q + 4];
            m1[q] = (b3 ? m1[q + 4] : m1[q]) + __shfl_xor(s1, 8);
            m2[q] = (b3 ? m2[q + 4] : m2[q]) + __shfl_xor(s2, 8);
        }
#pragma unroll
        for (int q = 0; q < 2; ++q) {
            float s1 = b2 ? m1[q] : m1[q + 2];
            float s2 = b2 ? m2[q] : m2[q + 2];
            m1[q] = (b2 ? m1[q + 2] : m1[q]) + __shfl_xor(s1, 4);
            m2[q] = (b2 ? m2[q + 2] : m2[q]) + __shfl_xor(s2, 4);
        }
        {
            float s1 = b1 ? m1[0] : m1[1];
            float s2 = b1 ? m2[0] : m2[1];
            m1[0] = (b1 ? m1[1] : m1[0]) + __shfl_xor(s1, 2);
            m2[0] = (b1 ? m2[1] : m2[0]) + __shfl_xor(s2, 2);
        }
        m1[0] += __shfl_xor(m1[0], 1);
        m2[0] += __shfl_xor(m2[0], 1);
        rs += __shfl_xor(rs, 16);
        rs += __shfl_xor(rs, 8);
        rs += __shfl_xor(rs, 4);
        rs += __shfl_xor(rs, 2);
        rs += __shfl_xor(rs, 1);
        const int e = j >> 1;            // this lane's pose element (row-major)

        const float inv_rs = 1.0f / rs;
        const float pe = m1[0] * inv_rs;
        const float ve = fmaxf(m2[0] * inv_rs - pe * pe, 0.0f) + EPS;
        const float lv = __logf(ve);

        // SL = sum log_var over the 16 elements (each e lives on 2 lanes -> x0.5)
        float SL = lv;
        SL += __shfl_xor(SL, 1);
        SL += __shfl_xor(SL, 2);
        SL += __shfl_xor(SL, 4);
        SL += __shfl_xor(SL, 8);
        SL += __shfl_xor(SL, 16);
        SL *= 0.5f;

        const float cost  = rs * (16.0f * bv_o + 0.5f * SL);
        const float logit = LAMBDA * (ba_o - cost);

        if (it == NITER - 1) {
            if ((j & 1) == 0) out[(b * NO + o) * 16 + e] = pe;
            if (j == 0) out[256000 + b * NO + o] = 1.0f / (1.0f + __expf(-logit));
            return;
        }

        const float log_a = (logit >= 0.0f) ? -log1pf(__expf(-logit))
                                            : logit - log1pf(__expf(logit));
        if ((j & 1) == 0) {
            sPoseM[o][e] = pe;
            sIvM[o][e]   = 1.0f / ve;
        }
        if (j == 0) sCo[o] = log_a - 0.5f * SL - 8.0f * LOG2PI;
        __syncthreads();   // B2: pose/iv/Co ready

        // ---------- e-step: q-form from stored (fp16) votes ----------
        {
            float pv[16], iv16[16];
            *(float4*)&pv[0]    = *(const float4*)&sPoseM[o][0];
            *(float4*)&pv[4]    = *(const float4*)&sPoseM[o][4];
            *(float4*)&pv[8]    = *(const float4*)&sPoseM[o][8];
            *(float4*)&pv[12]   = *(const float4*)&sPoseM[o][12];
            *(float4*)&iv16[0]  = *(const float4*)&sIvM[o][0];
            *(float4*)&iv16[4]  = *(const float4*)&sIvM[o][4];
            *(float4*)&iv16[8]  = *(const float4*)&sIvM[o][8];
            *(float4*)&iv16[12] = *(const float4*)&sIvM[o][12];
            const float Co = sCo[o];
#pragma unroll
            for (int k = 0; k < 7; ++k) {
                const int i = j + 32 * k;
                float q = 0.f;
#pragma unroll
                for (int p = 0; p < 8; ++p) {
                    const float2 f = __half22float2(vop[k][p]);
                    const float d0 = f.x - pv[2 * p];
                    const float d1 = f.y - pv[2 * p + 1];
                    q = fmaf(d0 * d0, iv16[2 * p], q);
                    q = fmaf(d1 * d1, iv16[2 * p + 1], q);
                }
                if (!(k == 6 && lastPartial)) {
                    sRaT[o][i] = Co - 0.5f * q;   // pre-normalization logit
                }
            }
        }
        __syncthreads();   // B3: logits ready

        // ---------- R update: softmax over o, times act ----------
        if (t < NI) {
            float l[16];
            float mx = -1e30f;
#pragma unroll
            for (int oo = 0; oo < 16; ++oo) { l[oo] = sRaT[oo][t]; mx = fmaxf(mx, l[oo]); }
            float s = 0.f;
#pragma unroll
            for (int oo = 0; oo < 16; ++oo) { l[oo] = __expf(l[oo] - mx); s += l[oo]; }
            const float sc = sAct[t] / s;
#pragma unroll
            for (int oo = 0; oo < 16; ++oo) sRaT[oo][t] = sc * l[oo];
        }
        __syncthreads();   // B4: Ra ready
    }
}

extern "C" void kernel_launch(void* const* d_in, const int* in_sizes, int n_in,
                              void* d_out, int out_size, void* d_ws, size_t ws_size,
                              hipStream_t stream) {
    const float* pose = (const float*)d_in[0];
    const float* actv = (const float*)d_in[1];
    const float* W    = (const float*)d_in[2];
    const float* bv   = (const float*)d_in[3];
    const float* ba   = (const float*)d_in[4];
    float* out = (float*)d_out;
    caps_em_kernel<<<dim3(1000), dim3(512), 0, stream>>>(pose, actv, W, bv, ba, out);
}

// Round 11
// 130.493 us; speedup vs baseline: 1.1474x; 1.0598x over previous
//
#include <hip/hip_runtime.h>
#include <hip/hip_fp16.h>

#define NITER 3
#define LAMBDA 0.01f
#define EPS 1e-9f
#define LOG2PI 1.8378770664093453f

#define DIN 12
#define CIN 8
#define NI 216      // 27 * 8 input capsule-taps
#define NO 16       // output capsules
#define PPAD 20     // sPT row stride (floats)
#define RSTR 216    // sRaT row stride (floats)

// 512 threads = 16 o x 32 j. Thread (o,j) owns taps i = j+32k (k=0..6, padded).
// Votes packed fp16 (vop[7][8] = 56 VGPR). Register budget engineered <= 96 TOTAL
// (unified VGPR+AGPR) so 2 blocks/CU co-reside (4 waves/SIMD, 2x R8/R10):
//  - per-k interleaved W-load/vote-compute (no 112-reg w[] prologue spike)
//  - m-step in two e-half sweeps: m1/m2[8] not [16]
//  - e-step in two halves with qacc[7]
__global__ __launch_bounds__(512)
void caps_em_kernel(const float* __restrict__ pose,
                    const float* __restrict__ act,
                    const float* __restrict__ W,
                    const float* __restrict__ beta_v,
                    const float* __restrict__ beta_a,
                    float* __restrict__ out)
{
    __shared__ __align__(16) float sPT[NI][PPAD];    // sPT[i][c*4+k] = P[i][k*4+c]
    __shared__ __align__(16) float sRaT[NO][RSTR];   // Ra transposed [o][i]
    __shared__ float sAct[NI];
    __shared__ __align__(16) float sPoseM[NO][16];   // row-major [o][r*4+c]
    __shared__ __align__(16) float sIvM[NO][16];
    __shared__ float sCo[NO];

    const int t = threadIdx.x;
    const int b = blockIdx.x;            // 0..999 -> (od,oh,ow)
    const int od = b / 100;
    const int rem = b - od * 100;
    const int oh = rem / 10;
    const int ow = rem - oh * 10;

    const int o = t >> 5;                // output capsule 0..15
    const int j = t & 31;                // i-lane 0..31

    // ---------- stage P (transposed) + act ----------
    for (int u = t; u < NI * 4; u += 512) {
        int i = u >> 2, q = u & 3;       // q = source row of the 4x4
        int ci = i & 7, n = i >> 3;
        int kw = n % 3, n2 = n / 3;
        int kh = n2 % 3, kd = n2 / 3;
        const float4 v = *(const float4*)&pose[((((od + kd) * DIN + (oh + kh)) * DIN + (ow + kw)) * CIN + ci) * 16 + q * 4];
        sPT[i][0 + q]  = v.x;
        sPT[i][4 + q]  = v.y;
        sPT[i][8 + q]  = v.z;
        sPT[i][12 + q] = v.w;
    }
    if (t < NI) {
        int i = t;
        int ci = i & 7, n = i >> 3;
        int kw = n % 3, n2 = n / 3;
        int kh = n2 % 3, kd = n2 / 3;
        sAct[i] = act[(((od + kd) * DIN + (oh + kh)) * DIN + (ow + kw)) * CIN + ci] + EPS;
    }
    const float bv_o = beta_v[o];
    const float ba_o = beta_a[o];
    __syncthreads();

    // ---------- votes ONCE, per-k interleaved load+compute (low reg spike) ----------
    const float4* W4 = (const float4*)W;        // idx = (i*16 + o)*4 + r
    __half2 vop[7][8];                          // vop[k][p] = (e=2p, e=2p+1)
#pragma unroll
    for (int k = 0; k < 7; ++k) {
        const int ip = min(j + 32 * k, NI - 1);
        const float4* Wp = W4 + (ip * 16 + o) * 4;
        const float4 w0 = Wp[0], w1 = Wp[1], w2 = Wp[2], w3 = Wp[3];
        float v16[16];
#pragma unroll
        for (int cc = 0; cc < 4; ++cc) {
            const float4 pt = *(const float4*)&sPT[ip][cc * 4];   // P[0..3][cc]
            v16[0 * 4 + cc]  = fmaf(w0.w, pt.w, fmaf(w0.z, pt.z, fmaf(w0.y, pt.y, w0.x * pt.x)));
            v16[1 * 4 + cc]  = fmaf(w1.w, pt.w, fmaf(w1.z, pt.z, fmaf(w1.y, pt.y, w1.x * pt.x)));
            v16[2 * 4 + cc]  = fmaf(w2.w, pt.w, fmaf(w2.z, pt.z, fmaf(w2.y, pt.y, w2.x * pt.x)));
            v16[3 * 4 + cc]  = fmaf(w3.w, pt.w, fmaf(w3.z, pt.z, fmaf(w3.y, pt.y, w3.x * pt.x)));
        }
#pragma unroll
        for (int p = 0; p < 8; ++p) {
            vop[k][p] = __floats2half2_rn(v16[2 * p], v16[2 * p + 1]);
        }
    }

    const int b4 = (j >> 4) & 1, b3 = (j >> 3) & 1, b2 = (j >> 2) & 1;
    const bool lastPartial = (j >= 24);  // k=6 tap i=192+j valid only for j<24
    const int eL = (j >> 2) & 7;         // this lane's element within each half

    for (int it = 0; it < NITER; ++it) {
        // ---------- ra for own taps ----------
        float rak[7];
#pragma unroll
        for (int k = 0; k < 7; ++k) {
            const int ip = min(j + 32 * k, NI - 1);
            float ra = (it == 0) ? sAct[ip] * 0.0625f : sRaT[o][ip];
            if (k == 6 && lastPartial) ra = 0.f;
            rak[k] = ra;
        }
        float rs = rak[0] + rak[1] + rak[2] + rak[3] + rak[4] + rak[5] + rak[6];
        rs += __shfl_xor(rs, 16);
        rs += __shfl_xor(rs, 8);
        rs += __shfl_xor(rs, 4);
        rs += __shfl_xor(rs, 2);
        rs += __shfl_xor(rs, 1);
        const float inv_rs = 1.0f / rs;

        float peA, ivA, lvA, peB, ivB, lvB;
        // ======== half sweeps: h=0 -> elements 0..7, h=1 -> 8..15 ========
#pragma unroll
        for (int h = 0; h < 2; ++h) {
            float m1[8], m2[8];
#pragma unroll
            for (int q = 0; q < 8; ++q) { m1[q] = 0.f; m2[q] = 0.f; }
#pragma unroll
            for (int k = 0; k < 7; ++k) {
                const float ra = rak[k];
#pragma unroll
                for (int p = 0; p < 4; ++p) {
                    const float2 f = __half22float2(vop[k][h * 4 + p]);
                    const float rv0 = ra * f.x;
                    const float rv1 = ra * f.y;
                    m1[2 * p]     += rv0;
                    m1[2 * p + 1] += rv1;
                    m2[2 * p]     = fmaf(rv0, f.x, m2[2 * p]);
                    m2[2 * p + 1] = fmaf(rv1, f.y, m2[2 * p + 1]);
                }
            }
            // 3-halving tree over 32 lanes: e_local = b4*4 + b3*2 + b2 = (j>>2)&7
#pragma unroll
            for (int q = 0; q < 4; ++q) {
                float s1 = b4 ? m1[q] : m1[q + 4];
                float s2 = b4 ? m2[q] : m2[q + 4];
                m1[q] = (b4 ? m1[q + 4] : m1[q]) + __shfl_xor(s1, 16);
                m2[q] = (b4 ? m2[q + 4] : m2[q]) + __shfl_xor(s2, 16);
            }
#pragma unroll
            for (int q = 0; q < 2; ++q) {
                float s1 = b3 ? m1[q] : m1[q + 2];
                float s2 = b3 ? m2[q] : m2[q + 2];
                m1[q] = (b3 ? m1[q + 2] : m1[q]) + __shfl_xor(s1, 8);
                m2[q] = (b3 ? m2[q + 2] : m2[q]) + __shfl_xor(s2, 8);
            }
            {
                float s1 = b2 ? m1[0] : m1[1];
                float s2 = b2 ? m2[0] : m2[1];
                m1[0] = (b2 ? m1[1] : m1[0]) + __shfl_xor(s1, 4);
                m2[0] = (b2 ? m2[1] : m2[0]) + __shfl_xor(s2, 4);
            }
            m1[0] += __shfl_xor(m1[0], 2);
            m2[0] += __shfl_xor(m2[0], 2);
            m1[0] += __shfl_xor(m1[0], 1);
            m2[0] += __shfl_xor(m2[0], 1);

            const float pe = m1[0] * inv_rs;
            const float ve = fmaxf(m2[0] * inv_rs - pe * pe, 0.0f) + EPS;
            if (h == 0) { peA = pe; ivA = 1.0f / ve; lvA = __logf(ve); }
            else        { peB = pe; ivB = 1.0f / ve; lvB = __logf(ve); }
        }

        // SL: each lane holds lv for 2 of 16 elements, 4-fold duplicated
        float SL = lvA + lvB;
        SL += __shfl_xor(SL, 1);
        SL += __shfl_xor(SL, 2);
        SL += __shfl_xor(SL, 4);
        SL += __shfl_xor(SL, 8);
        SL += __shfl_xor(SL, 16);
        SL *= 0.25f;

        const float cost  = rs * (16.0f * bv_o + 0.5f * SL);
        const float logit = LAMBDA * (ba_o - cost);

        if (it == NITER - 1) {
            if ((j & 3) == 0) {
                out[(b * NO + o) * 16 + eL]     = peA;
                out[(b * NO + o) * 16 + 8 + eL] = peB;
            }
            if (j == 0) out[256000 + b * NO + o] = 1.0f / (1.0f + __expf(-logit));
            return;
        }

        const float log_a = (logit >= 0.0f) ? -log1pf(__expf(-logit))
                                            : logit - log1pf(__expf(logit));
        if ((j & 3) == 0) {
            sPoseM[o][eL]     = peA;
            sPoseM[o][8 + eL] = peB;
            sIvM[o][eL]       = ivA;
            sIvM[o][8 + eL]   = ivB;
        }
        if (j == 0) sCo[o] = log_a - 0.5f * SL - 8.0f * LOG2PI;
        __syncthreads();   // B2: pose/iv/Co ready

        // ---------- e-step: q-form from stored votes, two halves, qacc[7] ----------
        float qacc[7];
#pragma unroll
        for (int k = 0; k < 7; ++k) qacc[k] = 0.f;
#pragma unroll
        for (int h = 0; h < 2; ++h) {
            float pv[8], iv8[8];
            *(float4*)&pv[0]  = *(const float4*)&sPoseM[o][h * 8];
            *(float4*)&pv[4]  = *(const float4*)&sPoseM[o][h * 8 + 4];
            *(float4*)&iv8[0] = *(const float4*)&sIvM[o][h * 8];
            *(float4*)&iv8[4] = *(const float4*)&sIvM[o][h * 8 + 4];
#pragma unroll
            for (int k = 0; k < 7; ++k) {
                float q = qacc[k];
#pragma unroll
                for (int p = 0; p < 4; ++p) {
                    const float2 f = __half22float2(vop[k][h * 4 + p]);
                    const float d0 = f.x - pv[2 * p];
                    const float d1 = f.y - pv[2 * p + 1];
                    q = fmaf(d0 * d0, iv8[2 * p], q);
                    q = fmaf(d1 * d1, iv8[2 * p + 1], q);
                }
                qacc[k] = q;
            }
        }
        {
            const float Co = sCo[o];
#pragma unroll
            for (int k = 0; k < 7; ++k) {
                if (!(k == 6 && lastPartial)) {
                    sRaT[o][j + 32 * k] = Co - 0.5f * qacc[k];   // pre-norm logit
                }
            }
        }
        __syncthreads();   // B3: logits ready

        // ---------- R update: softmax over o, times act ----------
        if (t < NI) {
            float l[16];
            float mx = -1e30f;
#pragma unroll
            for (int oo = 0; oo < 16; ++oo) { l[oo] = sRaT[oo][t]; mx = fmaxf(mx, l[oo]); }
            float s = 0.f;
#pragma unroll
            for (int oo = 0; oo < 16; ++oo) { l[oo] = __expf(l[oo] - mx); s += l[oo]; }
            const float sc = sAct[t] / s;
#pragma unroll
            for (int oo = 0; oo < 16; ++oo) sRaT[oo][t] = sc * l[oo];
        }
        __syncthreads();   // B4: Ra ready
    }
}

extern "C" void kernel_launch(void* const* d_in, const int* in_sizes, int n_in,
                              void* d_out, int out_size, void* d_ws, size_t ws_size,
                              hipStream_t stream) {
    const float* pose = (const float*)d_in[0];
    const float* actv = (const float*)d_in[1];
    const float* W    = (const float*)d_in[2];
    const float* bv   = (const float*)d_in[3];
    const float* ba   = (const float*)d_in[4];
    float* out = (float*)d_out;
    caps_em_kernel<<<dim3(1000), dim3(512), 0, stream>>>(pose, actv, W, bv, ba, out);
}